// Round 1
// baseline (363.068 us; speedup 1.0000x reference)
//
#include <hip/hip_runtime.h>
#include <stdint.h>

#define C_IN 256
#define C_MID 64
#define KOFF 9

typedef __attribute__((ext_vector_type(8))) short bf16x8;   // 8 bf16 = 4 VGPRs
typedef __attribute__((ext_vector_type(4))) float f32x4;    // MFMA C/D
typedef __attribute__((ext_vector_type(4))) float float4v;

// fp32 -> bf16 round-to-nearest-even
__device__ inline unsigned short f2bf(float f) {
    union { float f; unsigned u; } x; x.f = f;
    unsigned r = x.u + 0x7FFFu + ((x.u >> 16) & 1u);
    return (unsigned short)(r >> 16);
}

// ---------------------------------------------------------------------------
// prep: fold BN scales into weights, transpose to B-fragment-friendly layouts,
// convert to bf16, zero the sentinel gather row. Re-runs every call (ws is
// re-poisoned by the harness).
//   w1t[n][k] = bf16(w1[k][n] * s1[n])          [64][256]
//   w2t[k][d][c] = bf16(w2[k][c][d] * s2[d])    [9][64][64]
//   w3t[e][c] = bf16(w3[c][e] * s3[e])          [256][64]
// ---------------------------------------------------------------------------
__global__ void prep_kernel(const float* __restrict__ w1, const float* __restrict__ s1,
                            const float* __restrict__ w2, const float* __restrict__ s2,
                            const float* __restrict__ w3, const float* __restrict__ s3,
                            unsigned short* __restrict__ w1t,
                            unsigned short* __restrict__ w2t,
                            unsigned short* __restrict__ w3t,
                            unsigned short* __restrict__ zrow) {
    int tid = blockIdx.x * blockDim.x + threadIdx.x;
    int stride = gridDim.x * blockDim.x;
    for (int i = tid; i < C_MID * C_IN; i += stride) {
        int n = i / C_IN, k = i % C_IN;
        w1t[i] = f2bf(w1[k * C_MID + n] * s1[n]);
    }
    for (int i = tid; i < KOFF * C_MID * C_MID; i += stride) {
        int k = i / (C_MID * C_MID);
        int r = i % (C_MID * C_MID);
        int d = r / C_MID, c = r % C_MID;
        w2t[i] = f2bf(w2[(k * C_MID + c) * C_MID + d] * s2[d]);
    }
    for (int i = tid; i < C_IN * C_MID; i += stride) {
        int e = i / C_MID, c = i % C_MID;
        w3t[i] = f2bf(w3[c * C_IN + e] * s3[e]);
    }
    for (int i = tid; i < C_MID; i += stride) zrow[i] = 0;
}

// ---------------------------------------------------------------------------
// conv1: out1[n][d] = relu(feat[n][:] @ w1[:, d] * s1[d] + b1[d]) as bf16.
// 4 waves/block, 16 rows/wave, mfma_f32_16x16x32_bf16.
// A loaded directly from global fp32 (rows are wave-private -> no LDS).
// ---------------------------------------------------------------------------
__global__ __launch_bounds__(256) void conv1_kernel(
    const float* __restrict__ feat, const unsigned short* __restrict__ w1t,
    const float* __restrict__ b1, unsigned short* __restrict__ out1, int N)
{
    int wave = threadIdx.x >> 6;
    int lane = threadIdx.x & 63;
    int l15 = lane & 15;
    int quad = lane >> 4;
    int row_base = blockIdx.x * 64 + wave * 16;
    int arow = row_base + l15;
    int arowc = arow < N ? arow : (N - 1);

    const float4v* pa = reinterpret_cast<const float4v*>(feat + arowc * C_IN + quad * 8);
    const bf16x8* pb = reinterpret_cast<const bf16x8*>(w1t);

    float b1v[4];
#pragma unroll
    for (int ct = 0; ct < 4; ++ct) b1v[ct] = b1[ct * 16 + l15];

    f32x4 acc[4] = {};
#pragma unroll
    for (int kk = 0; kk < 8; ++kk) {          // K = 256 in steps of 32
        float4v a0 = pa[kk * 8];
        float4v a1 = pa[kk * 8 + 1];
        union { unsigned short s[8]; bf16x8 v; } ua;
#pragma unroll
        for (int j = 0; j < 4; ++j) { ua.s[j] = f2bf(a0[j]); ua.s[4 + j] = f2bf(a1[j]); }
#pragma unroll
        for (int ct = 0; ct < 4; ++ct) {
            bf16x8 fb = pb[(ct * 16 + l15) * 32 + kk * 4 + quad];
            acc[ct] = __builtin_amdgcn_mfma_f32_16x16x32_bf16(ua.v, fb, acc[ct], 0, 0, 0);
        }
    }
    // C/D layout: col = lane&15 (+ct*16), row = quad*4 + reg
#pragma unroll
    for (int ct = 0; ct < 4; ++ct) {
#pragma unroll
        for (int reg = 0; reg < 4; ++reg) {
            int row = row_base + quad * 4 + reg;
            if (row < N) {
                float v = acc[ct][reg] + b1v[ct];
                v = fmaxf(v, 0.f);
                out1[row * C_MID + ct * 16 + l15] = f2bf(v);
            }
        }
    }
}

// ---------------------------------------------------------------------------
// conv2 + conv3 fused.
// conv2: acc2[n][d] = sum_k sum_c out1[nbr[n][k]][c] * w2t[k][d][c]
//        (sentinel nbr==N hits the zeroed row -> branch-free gather)
// mid = relu(acc2 + b2) -> per-wave LDS tile (C-layout -> A-layout transpose)
// conv3: out[n][e] = relu(mid[n][:] @ w3t[e][:] + b3[e] + feat[n][e])
// ---------------------------------------------------------------------------
__global__ __launch_bounds__(256) void conv23_kernel(
    const float* __restrict__ feat, const int* __restrict__ nbr,
    const unsigned short* __restrict__ out1, const unsigned short* __restrict__ w2t,
    const float* __restrict__ b2, const unsigned short* __restrict__ w3t,
    const float* __restrict__ b3, float* __restrict__ out, int N)
{
    __shared__ __align__(16) unsigned short mid[4][16][72];  // +8 pad breaks bank stride

    int wave = threadIdx.x >> 6;
    int lane = threadIdx.x & 63;
    int l15 = lane & 15;
    int quad = lane >> 4;
    int row_base = blockIdx.x * 64 + wave * 16;
    int arow = row_base + l15;
    int arowc = arow < N ? arow : (N - 1);

    const bf16x8* pw2 = reinterpret_cast<const bf16x8*>(w2t);
    f32x4 acc2[4] = {};
#pragma unroll
    for (int k = 0; k < KOFF; ++k) {
        int nb = nbr[arowc * KOFF + k];       // in [0, N]; row N is zeros
        const bf16x8* pg = reinterpret_cast<const bf16x8*>(out1 + nb * C_MID + quad * 8);
#pragma unroll
        for (int kk = 0; kk < 2; ++kk) {      // K = 64 in steps of 32
            bf16x8 fa = pg[kk * 4];
#pragma unroll
            for (int ct = 0; ct < 4; ++ct) {
                bf16x8 fb = pw2[k * 512 + (ct * 16 + l15) * 8 + kk * 4 + quad];
                acc2[ct] = __builtin_amdgcn_mfma_f32_16x16x32_bf16(fa, fb, acc2[ct], 0, 0, 0);
            }
        }
    }
    // conv2 epilogue -> LDS (transpose C-layout to A-layout)
#pragma unroll
    for (int ct = 0; ct < 4; ++ct) {
        float bb = b2[ct * 16 + l15];
#pragma unroll
        for (int reg = 0; reg < 4; ++reg) {
            float v = fmaxf(acc2[ct][reg] + bb, 0.f);
            mid[wave][quad * 4 + reg][ct * 16 + l15] = f2bf(v);
        }
    }
    __syncthreads();

    const bf16x8* pw3 = reinterpret_cast<const bf16x8*>(w3t);
    f32x4 acc3[16] = {};
#pragma unroll
    for (int kk = 0; kk < 2; ++kk) {          // K = 64 in steps of 32
        bf16x8 fa = *reinterpret_cast<const bf16x8*>(&mid[wave][l15][kk * 32 + quad * 8]);
#pragma unroll
        for (int ct = 0; ct < 16; ++ct) {
            bf16x8 fb = pw3[(ct * 16 + l15) * 8 + kk * 4 + quad];
            acc3[ct] = __builtin_amdgcn_mfma_f32_16x16x32_bf16(fa, fb, acc3[ct], 0, 0, 0);
        }
    }
    // conv3 epilogue: bias + fp32 residual + relu
#pragma unroll
    for (int ct = 0; ct < 16; ++ct) {
        float bb = b3[ct * 16 + l15];
#pragma unroll
        for (int reg = 0; reg < 4; ++reg) {
            int row = row_base + quad * 4 + reg;
            if (row < N) {
                int o = row * C_IN + ct * 16 + l15;
                float v = acc3[ct][reg] + bb + feat[o];
                out[o] = fmaxf(v, 0.f);
            }
        }
    }
}

extern "C" void kernel_launch(void* const* d_in, const int* in_sizes, int n_in,
                              void* d_out, int out_size, void* d_ws, size_t ws_size,
                              hipStream_t stream) {
    const float* feat = (const float*)d_in[0];
    const int*   nbr  = (const int*)d_in[1];
    const float* w1   = (const float*)d_in[2];
    const float* s1   = (const float*)d_in[3];
    const float* b1   = (const float*)d_in[4];
    const float* w2   = (const float*)d_in[5];
    const float* s2   = (const float*)d_in[6];
    const float* b2   = (const float*)d_in[7];
    const float* w3   = (const float*)d_in[8];
    const float* s3   = (const float*)d_in[9];
    const float* b3   = (const float*)d_in[10];
    float* out = (float*)d_out;
    int N = in_sizes[0] / C_IN;

    char* ws = (char*)d_ws;
    unsigned short* w1t  = (unsigned short*)(ws);                    // 32768 B
    unsigned short* w2t  = (unsigned short*)(ws + 32768);            // 73728 B
    unsigned short* w3t  = (unsigned short*)(ws + 32768 + 73728);    // 32768 B
    unsigned short* out1 = (unsigned short*)(ws + 139264);           // (N+1)*64*2 B

    prep_kernel<<<80, 256, 0, stream>>>(w1, s1, w2, s2, w3, s3, w1t, w2t, w3t,
                                        out1 + (size_t)N * C_MID);
    int nblk = (N + 63) / 64;
    conv1_kernel<<<nblk, 256, 0, stream>>>(feat, w1t, b1, out1, N);
    conv23_kernel<<<nblk, 256, 0, stream>>>(feat, nbr, out1, w2t, b2, w3t, b3, out, N);
}